// Round 4
// baseline (857.750 us; speedup 1.0000x reference)
//
#include <hip/hip_runtime.h>
#include <stdint.h>

#define NUM_CLASSES 81
#define MAX_BOXES 300
#define NEG_SCORE (-1000000000.0f)
#define IOU_THR 0.4f
#define MMAX 2048
#define MWORDS (MMAX / 64)   // 32

// ---- workspace layout (bytes) ----
static constexpr size_t OFF_SCORES = 0;               // 300000 * 4 = 1.2 MB
static constexpr size_t OFF_CAREA  = 0x1F0000;        // MMAX f32 (8 KB)
static constexpr size_t OFF_ZERO   = 0x200000;        // zeroed region: ctrl(64B) rank(8KB) hist(256KB)
static constexpr size_t ZERO_BYTES = 64 + MMAX * 4 + 65536 * 4;
static constexpr size_t OFF_KEYS   = 0x250000;        // MMAX u64 (16 KB)
static constexpr size_t OFF_CIDX   = 0x260000;        // MMAX int (8 KB)
static constexpr size_t OFF_CBOX   = 0x264000;        // MMAX float4 (32 KB)
static constexpr size_t OFF_ACC    = 0x270000;        // 300 int
static constexpr size_t OFF_MATRIX = 0x280000;        // MMAX * MWORDS u64 = 512 KB

__device__ __forceinline__ uint32_t float_ordered(float f) {
    uint32_t b = __float_as_uint(f);
    return (b & 0x80000000u) ? ~b : (b | 0x80000000u);
}

__device__ __forceinline__ uint64_t readlane_u64(uint64_t v, int srclane) {
    uint32_t lo = (uint32_t)__builtin_amdgcn_readlane((int)(uint32_t)v, srclane);
    uint32_t hi = (uint32_t)__builtin_amdgcn_readlane((int)(uint32_t)(v >> 32), srclane);
    return ((uint64_t)hi << 32) | lo;
}

// A: 16 lanes per box, direct coalesced global dword loads, no LDS.
// Lane q reads elements q, q+16, ..., q+64 (5 independent loads); lane 15 folds
// element 80. 4x shfl_xor reduce -> box max in all 16 lanes. Lane q==0 holds
// element 0 (v[0]) for the argmax==0 test, writes score + hist atomic.
__global__ void score_kernel(const float* __restrict__ cls, float* __restrict__ scores,
                             uint32_t* __restrict__ hist, int n) {
    const int l = threadIdx.x & 63;
    const int q = l & 15;
    const int box = blockIdx.x * 16 + (threadIdx.x >> 4);  // 256 thr = 16 boxes/block
    const int cbox = box < n ? box : n - 1;
    const float* row = cls + (size_t)cbox * NUM_CLASSES;

    float v[5];
    #pragma unroll
    for (int it = 0; it < 5; ++it) v[it] = row[it * 16 + q];
    float e80 = row[80];

    float m = v[0];
    #pragma unroll
    for (int it = 1; it < 5; ++it) m = fmaxf(m, v[it]);
    m = (q == 15) ? fmaxf(m, e80) : m;
    m = fmaxf(m, __shfl_xor(m, 1));
    m = fmaxf(m, __shfl_xor(m, 2));
    m = fmaxf(m, __shfl_xor(m, 4));
    m = fmaxf(m, __shfl_xor(m, 8));

    if (q == 0 && box < n) {
        float sc = (v[0] == m) ? NEG_SCORE : m;  // v[0]<=m always; equality => argmax==0
        scores[box] = sc;
        if (sc != NEG_SCORE) atomicAdd(&hist[float_ordered(sc) >> 16], 1u);
    }
}

// T: one block. Threshold thr (16-bit) s.t. #{o>>16 >= thr} <= MMAX, via LDS suffix sums.
__global__ void threshold_kernel(const uint32_t* __restrict__ hist, uint32_t* __restrict__ ctrl) {
    __shared__ uint32_t csum[256];
    __shared__ uint32_t binv[256];
    __shared__ int sC;
    __shared__ uint32_t sAcc;
    __shared__ uint32_t sF;
    int t = threadIdx.x;
    if (t == 0) { sC = -1; sAcc = 0; sF = 256; }
    uint32_t s = 0;
    const uint32_t* hp = hist + t * 256;
    for (int b = 0; b < 256; ++b) s += hp[b];
    csum[t] = s;
    __syncthreads();
    uint32_t S = 0;
    for (int c = t; c < 256; ++c) S += csum[c];   // S(t) = sum chunks >= t
    uint32_t St1 = S - csum[t];                   // S(t+1)
    if (S > MMAX && St1 <= MMAX) { sC = t; sAcc = St1; }
    __syncthreads();
    int C = sC;
    uint32_t thr = 0;
    if (C >= 0) {
        binv[t] = hist[C * 256 + t];
        __syncthreads();
        uint32_t R = MMAX - sAcc;
        uint32_t SB_ = 0;
        for (int b = t; b < 256; ++b) SB_ += binv[b];  // SB(t) = sum bins >= t
        bool ok = SB_ <= R;
        bool okprev = (t == 0) ? false : ((SB_ + binv[t - 1]) <= R);
        if (ok && !okprev) sF = (uint32_t)t;           // F = min b with SB(b) <= R
        __syncthreads();
        thr = ((uint32_t)C << 8) + sF;                 // F==256 rolls into next chunk
    }
    if (t == 0) ctrl[2] = thr;
}

// F: compact keys = (ordered<<32)|~idx for scores above threshold
__global__ void compact_kernel(const float* __restrict__ scores, uint32_t* __restrict__ ctrl,
                               uint64_t* __restrict__ keys, int n) {
    __shared__ uint32_t sThr;
    if (threadIdx.x == 0) sThr = ctrl[2];
    __syncthreads();
    uint32_t thr = sThr;
    for (int i = blockIdx.x * blockDim.x + threadIdx.x; i < n; i += gridDim.x * blockDim.x) {
        uint32_t o = float_ordered(scores[i]);
        if ((o >> 16) >= thr) {
            uint32_t pos = atomicAdd(&ctrl[0], 1u);
            if (pos < MMAX)
                keys[pos] = ((uint64_t)o << 32) | (uint32_t)(~(uint32_t)i);
        }
    }
}

// G1: brute-force rank: rank[c] = #{j : key_j > key_c}, tiled 256x256 via LDS
__global__ void rank_partial_kernel(const uint64_t* __restrict__ keys, const uint32_t* __restrict__ ctrl,
                                    uint32_t* __restrict__ rank) {
    __shared__ uint64_t kk[256];
    int M = (int)ctrl[0]; if (M > MMAX) M = MMAX;
    int cbase = blockIdx.x * 256;
    int jbase = blockIdx.y * 256;
    if (cbase >= M || jbase >= M) return;
    int t = threadIdx.x;
    int j = jbase + t;
    kk[t] = (j < M) ? keys[j] : 0ull;  // 0 never exceeds a candidate key (top bit set)
    __syncthreads();
    int c = cbase + t;
    if (c >= M) return;
    uint64_t k = keys[c];
    int cnt = 0;
    #pragma unroll 8
    for (int u = 0; u < 256; ++u) cnt += (kk[u] > k) ? 1 : 0;
    if (cnt) atomicAdd(&rank[c], (uint32_t)cnt);
}

// G2: scatter into sorted order; gather candidate boxes + areas
__global__ void scatter_kernel(const uint64_t* __restrict__ keys, const uint32_t* __restrict__ rank,
                               const uint32_t* __restrict__ ctrl, const float* __restrict__ boxes,
                               int* __restrict__ csorted_idx, float4* __restrict__ csorted_box,
                               float* __restrict__ careas) {
    int M = (int)ctrl[0]; if (M > MMAX) M = MMAX;
    int c = blockIdx.x * blockDim.x + threadIdx.x;
    if (c >= M) return;
    uint64_t k = keys[c];
    uint32_t r = rank[c];
    uint32_t idx = ~(uint32_t)k;
    float4 b = *(const float4*)(boxes + (size_t)idx * 4);
    csorted_idx[r] = (int)idx;
    csorted_box[r] = b;
    careas[r] = fmaxf(b.z - b.x, 0.f) * fmaxf(b.w - b.y, 0.f);
}

// H: pairwise IoU suppression bitmask, upper-triangle words only (w >= i>>6).
__global__ void matrix_kernel(const float4* __restrict__ cbox, const float* __restrict__ careas,
                              const uint32_t* __restrict__ ctrl, uint64_t* __restrict__ matrix) {
    int i = blockIdx.x;
    int M = (int)ctrl[0]; if (M > MMAX) M = MMAX;
    if (i >= M) return;
    int lane = threadIdx.x & 63;
    int wave = threadIdx.x >> 6;  // 4 waves per block
    float4 bi = cbox[i];
    float ai = careas[i];
    int w0 = i >> 6;
    for (int w = w0 + wave; w < MWORDS; w += 4) {
        int j = (w << 6) | lane;
        bool sup = false;
        if (j < M) {
            float4 bj = cbox[j];
            float xx1 = fmaxf(bi.x, bj.x);
            float yy1 = fmaxf(bi.y, bj.y);
            float xx2 = fminf(bi.z, bj.z);
            float yy2 = fminf(bi.w, bj.w);
            float inter = fmaxf(xx2 - xx1, 0.f) * fmaxf(yy2 - yy1, 0.f);
            float uni = ai + careas[j] - inter;
            float iou = inter / fmaxf(uni, 1e-8f);
            sup = iou > IOU_THR;
        }
        uint64_t word = __ballot(sup ? 1 : 0);
        if (lane == 0) matrix[(size_t)i * MWORDS + w] = word;
    }
}

// I: sequential greedy scan, one wave. Removed bitmask in lanes 0..31 (1 u64 each).
#define LOADBLK(ARR, b0)                                                       \
    {                                                                          \
        _Pragma("unroll")                                                      \
        for (int r_ = 0; r_ < 32; ++r_) {                                      \
            int row_ = (b0) + r_;                                              \
            row_ = row_ < MMAX ? row_ : MMAX - 1;                              \
            ARR[r_] = matrix[(size_t)row_ * MWORDS + (lane & 31)];             \
        }                                                                      \
    }

#define PROCBLK(ARR, b0, REFRESH_AT0)                                          \
    {                                                                          \
        _Pragma("unroll")                                                      \
        for (int r_ = 0; r_ < 32; ++r_) {                                      \
            int i_ = (b0) + r_;                                                \
            if ((REFRESH_AT0) && r_ == 0) {                                    \
                wrd = readlane_u64(removed, i_ >> 6);                          \
            }                                                                  \
            if (i_ < M && acc < MAX_BOXES && !((wrd >> (i_ & 63)) & 1ull)) {   \
                if (lane == 0) accepted[acc] = i_;                             \
                removed |= ARR[r_];                                            \
                wrd = readlane_u64(removed, i_ >> 6);                          \
                ++acc;                                                         \
            }                                                                  \
        }                                                                      \
    }

__global__ void scan_kernel(const uint64_t* __restrict__ matrix, uint32_t* __restrict__ ctrl,
                            int* __restrict__ accepted) {
    const int lane = threadIdx.x;
    int M = (int)ctrl[0]; if (M > MMAX) M = MMAX;
    uint64_t removed = 0;
    uint64_t wrd = 0;
    int acc = 0;
    uint64_t A[32], B[32];

    LOADBLK(A, 0);
    for (int base = 0; base < M && acc < MAX_BOXES; base += 64) {
        LOADBLK(B, base + 32);
        PROCBLK(A, base, true);
        LOADBLK(A, base + 64);
        PROCBLK(B, base + 32, false);
    }
    if (lane == 0) ctrl[1] = (uint32_t)acc;
}
#undef LOADBLK
#undef PROCBLK

// J: write all 25500 outputs (zeros for invalid slots)
__global__ void output_kernel(const float* __restrict__ boxes, const float* __restrict__ cls,
                              const int* __restrict__ csorted_idx, const int* __restrict__ accepted,
                              const uint32_t* __restrict__ ctrl, float* __restrict__ out, int total) {
    int e = blockIdx.x * blockDim.x + threadIdx.x;
    if (e >= total) return;
    int acc = (int)ctrl[1];
    float val = 0.0f;
    if (e < MAX_BOXES * 4) {
        int s = e >> 2, f = e & 3;
        if (s < acc) {
            int orig = csorted_idx[accepted[s]];
            val = boxes[(size_t)orig * 4 + f];
        }
    } else {
        int e2 = e - MAX_BOXES * 4;
        int s = e2 / NUM_CLASSES;
        int c = e2 - s * NUM_CLASSES;
        if (s < acc) {
            int orig = csorted_idx[accepted[s]];
            val = cls[(size_t)orig * NUM_CLASSES + c];
        }
    }
    out[e] = val;
}

extern "C" void kernel_launch(void* const* d_in, const int* in_sizes, int n_in,
                              void* d_out, int out_size, void* d_ws, size_t ws_size,
                              hipStream_t stream) {
    const float* boxes = (const float*)d_in[0];
    const float* cls   = (const float*)d_in[1];
    float* out = (float*)d_out;
    const int N = in_sizes[0] / 4;

    char* ws = (char*)d_ws;
    float*     scores      = (float*)(ws + OFF_SCORES);
    float*     careas      = (float*)(ws + OFF_CAREA);
    uint32_t*  ctrl        = (uint32_t*)(ws + OFF_ZERO);
    uint32_t*  rank        = (uint32_t*)(ws + OFF_ZERO + 64);
    uint32_t*  hist        = (uint32_t*)(ws + OFF_ZERO + 64 + MMAX * 4);
    uint64_t*  keys        = (uint64_t*)(ws + OFF_KEYS);
    int*       csorted_idx = (int*)(ws + OFF_CIDX);
    float4*    csorted_box = (float4*)(ws + OFF_CBOX);
    int*       accepted    = (int*)(ws + OFF_ACC);
    uint64_t*  matrix      = (uint64_t*)(ws + OFF_MATRIX);

    hipMemsetAsync(ws + OFF_ZERO, 0, ZERO_BYTES, stream);
    score_kernel<<<(N + 15) / 16, 256, 0, stream>>>(cls, scores, hist, N);
    threshold_kernel<<<1, 256, 0, stream>>>(hist, ctrl);
    compact_kernel<<<512, 256, 0, stream>>>(scores, ctrl, keys, N);
    rank_partial_kernel<<<dim3(MMAX / 256, MMAX / 256), 256, 0, stream>>>(keys, ctrl, rank);
    scatter_kernel<<<MMAX / 256, 256, 0, stream>>>(keys, rank, ctrl, boxes, csorted_idx,
                                                   csorted_box, careas);
    matrix_kernel<<<MMAX, 256, 0, stream>>>(csorted_box, careas, ctrl, matrix);
    scan_kernel<<<1, 64, 0, stream>>>(matrix, ctrl, accepted);
    output_kernel<<<(out_size + 255) / 256, 256, 0, stream>>>(boxes, cls, csorted_idx, accepted,
                                                              ctrl, out, out_size);
}

// Round 5
// 132.367 us; speedup vs baseline: 6.4801x; 6.4801x over previous
//
#include <hip/hip_runtime.h>
#include <stdint.h>

#define NUM_CLASSES 81
#define MAX_BOXES 300
#define NEG_SCORE (-1000000000.0f)
#define IOU_THR 0.4f
#define MMAX 2048
#define MWORDS (MMAX / 64)   // 32

// ---- workspace layout (bytes) ----
static constexpr size_t OFF_SCORES = 0;               // 300000 * 4 = 1.2 MB
static constexpr size_t OFF_CAREA  = 0x1F0000;        // MMAX f32 (8 KB)
static constexpr size_t OFF_COARSE = 0x200000;        // 256 u32
static constexpr size_t OFF_FINE   = 0x201000;        // 256 u32
static constexpr size_t OFF_CTRL   = 0x202000;        // [0]=cand_count [1]=acc_count
static constexpr size_t OFF_RANK   = 0x203000;        // MMAX u32 (8 KB)
static constexpr size_t OFF_KEYS   = 0x208000;        // MMAX u64 (16 KB)
static constexpr size_t OFF_CIDX   = 0x210000;        // MMAX int (8 KB)
static constexpr size_t OFF_CBOX   = 0x214000;        // MMAX float4 (32 KB)
static constexpr size_t OFF_ACC    = 0x224000;        // 300 int
static constexpr size_t OFF_MATRIX = 0x228000;        // MMAX * MWORDS u64 = 512 KB

__device__ __forceinline__ uint32_t float_ordered(float f) {
    uint32_t b = __float_as_uint(f);
    return (b & 0x80000000u) ? ~b : (b | 0x80000000u);
}

__device__ __forceinline__ uint64_t readlane_u64(uint64_t v, int srclane) {
    uint32_t lo = (uint32_t)__builtin_amdgcn_readlane((int)(uint32_t)v, srclane);
    uint32_t hi = (uint32_t)__builtin_amdgcn_readlane((int)(uint32_t)(v >> 32), srclane);
    return ((uint64_t)hi << 32) | lo;
}

// A: 16 lanes per box, direct coalesced global dword loads, no LDS, NO atomics.
// Lane q reads elements q, q+16, ..., q+64 (5 independent loads); lane 15 folds
// element 80. 4x shfl_xor reduce -> box max across the 16-lane group. Lane q==0
// holds element 0 (v[0]) for the argmax==0 test and writes the score.
// Block 0 additionally zeroes hists / counters / ranks (init fold; no consumer
// of those buffers runs before this kernel completes).
__global__ void score_kernel(const float* __restrict__ cls, float* __restrict__ scores,
                             uint32_t* __restrict__ coarse, uint32_t* __restrict__ fine,
                             uint32_t* __restrict__ ctrl, uint32_t* __restrict__ rank, int n) {
    if (blockIdx.x == 0) {
        int t = threadIdx.x;
        if (t < 256) { coarse[t] = 0; fine[t] = 0; }
        if (t < 8) ctrl[t] = 0;
        for (int r = t; r < MMAX; r += 256) rank[r] = 0;
    }
    const int q = threadIdx.x & 15;
    const int box = blockIdx.x * 16 + (threadIdx.x >> 4);  // 256 thr = 16 boxes/block
    const int cbox = box < n ? box : n - 1;
    const float* row = cls + (size_t)cbox * NUM_CLASSES;

    float v[5];
    #pragma unroll
    for (int it = 0; it < 5; ++it) v[it] = row[it * 16 + q];
    float e80 = row[80];

    float m = v[0];
    #pragma unroll
    for (int it = 1; it < 5; ++it) m = fmaxf(m, v[it]);
    m = (q == 15) ? fmaxf(m, e80) : m;
    m = fmaxf(m, __shfl_xor(m, 1));
    m = fmaxf(m, __shfl_xor(m, 2));
    m = fmaxf(m, __shfl_xor(m, 4));
    m = fmaxf(m, __shfl_xor(m, 8));

    if (q == 0 && box < n) {
        scores[box] = (v[0] == m) ? NEG_SCORE : m;  // v[0]<=m always; equality => argmax==0
    }
}

// B: coarse 256-bin histogram on top-8 ordered bits (LDS aggregate -> global)
__global__ void coarse_hist_kernel(const float* __restrict__ scores, uint32_t* __restrict__ coarse, int n) {
    __shared__ uint32_t h[256];
    for (int t = threadIdx.x; t < 256; t += blockDim.x) h[t] = 0;
    __syncthreads();
    for (int i = blockIdx.x * blockDim.x + threadIdx.x; i < n; i += gridDim.x * blockDim.x) {
        uint32_t o = float_ordered(scores[i]);
        atomicAdd(&h[o >> 24], 1u);
    }
    __syncthreads();
    for (int t = threadIdx.x; t < 256; t += blockDim.x)
        if (h[t]) atomicAdd(&coarse[t], h[t]);
}

// pick the coarse bin C containing the MMAX-th element; returns -1 if total <= MMAX
__device__ __forceinline__ int select_coarse(const uint32_t* coarse, uint32_t* above_out) {
    uint32_t s = 0;
    for (int c = 255; c >= 0; --c) {
        uint32_t sc = s + coarse[c];
        if (sc > MMAX) { *above_out = s; return c; }
        s = sc;
    }
    *above_out = s;
    return -1;
}

// D: fine 256-bin histogram of elements inside coarse bin C (next 8 ordered bits)
__global__ void fine_hist_kernel(const float* __restrict__ scores, const uint32_t* __restrict__ coarse,
                                 uint32_t* __restrict__ fine, int n) {
    __shared__ int sC;
    __shared__ uint32_t h[256];
    if (threadIdx.x == 0) {
        uint32_t above;
        sC = select_coarse(coarse, &above);
    }
    for (int t = threadIdx.x; t < 256; t += blockDim.x) h[t] = 0;
    __syncthreads();
    int C = sC;
    if (C < 0) return;
    for (int i = blockIdx.x * blockDim.x + threadIdx.x; i < n; i += gridDim.x * blockDim.x) {
        uint32_t o = float_ordered(scores[i]);
        if ((int)(o >> 24) == C) atomicAdd(&h[(o >> 16) & 255u], 1u);
    }
    __syncthreads();
    for (int t = threadIdx.x; t < 256; t += blockDim.x)
        if (h[t]) atomicAdd(&fine[t], h[t]);
}

// F: compute 16-bit threshold (<= MMAX candidates), compact keys = (ordered<<32)|~idx
__global__ void compact_kernel(const float* __restrict__ scores, const uint32_t* __restrict__ coarse,
                               const uint32_t* __restrict__ fine, uint32_t* __restrict__ ctrl,
                               uint64_t* __restrict__ keys, int n) {
    __shared__ uint32_t sThr;
    if (threadIdx.x == 0) {
        uint32_t above;
        int C = select_coarse(coarse, &above);
        uint32_t thr;
        if (C < 0) {
            thr = 0;
        } else {
            uint32_t R = MMAX - above;
            uint32_t g = 0, F = 0;
            for (int f = 255; f >= 0; --f) {
                uint32_t gf = g + fine[f];
                if (gf > R) { F = (uint32_t)f + 1u; break; }
                g = gf;
            }
            thr = ((uint32_t)C << 8) | F;
        }
        sThr = thr;
    }
    __syncthreads();
    uint32_t thr = sThr;
    for (int i = blockIdx.x * blockDim.x + threadIdx.x; i < n; i += gridDim.x * blockDim.x) {
        uint32_t o = float_ordered(scores[i]);
        if ((o >> 16) >= thr) {
            uint32_t pos = atomicAdd(&ctrl[0], 1u);
            if (pos < MMAX)
                keys[pos] = ((uint64_t)o << 32) | (uint32_t)(~(uint32_t)i);
        }
    }
}

// G1: brute-force rank: rank[c] = #{j : key_j > key_c}, tiled 256x256 via LDS
__global__ void rank_partial_kernel(const uint64_t* __restrict__ keys, const uint32_t* __restrict__ ctrl,
                                    uint32_t* __restrict__ rank) {
    __shared__ uint64_t kk[256];
    int M = (int)ctrl[0]; if (M > MMAX) M = MMAX;
    int cbase = blockIdx.x * 256;
    int jbase = blockIdx.y * 256;
    if (cbase >= M || jbase >= M) return;
    int t = threadIdx.x;
    int j = jbase + t;
    kk[t] = (j < M) ? keys[j] : 0ull;  // 0 never exceeds a candidate key (top bit set)
    __syncthreads();
    int c = cbase + t;
    if (c >= M) return;
    uint64_t k = keys[c];
    int cnt = 0;
    #pragma unroll 8
    for (int u = 0; u < 256; ++u) cnt += (kk[u] > k) ? 1 : 0;
    if (cnt) atomicAdd(&rank[c], (uint32_t)cnt);
}

// G2: scatter into sorted order; gather candidate boxes + areas
__global__ void scatter_kernel(const uint64_t* __restrict__ keys, const uint32_t* __restrict__ rank,
                               const uint32_t* __restrict__ ctrl, const float* __restrict__ boxes,
                               int* __restrict__ csorted_idx, float4* __restrict__ csorted_box,
                               float* __restrict__ careas) {
    int M = (int)ctrl[0]; if (M > MMAX) M = MMAX;
    int c = blockIdx.x * blockDim.x + threadIdx.x;
    if (c >= M) return;
    uint64_t k = keys[c];
    uint32_t r = rank[c];
    uint32_t idx = ~(uint32_t)k;
    float4 b = *(const float4*)(boxes + (size_t)idx * 4);
    csorted_idx[r] = (int)idx;
    csorted_box[r] = b;
    careas[r] = fmaxf(b.z - b.x, 0.f) * fmaxf(b.w - b.y, 0.f);
}

// H: pairwise IoU suppression bitmask, upper-triangle words only (w >= i>>6).
// Lower words stay unwritten: the scan consults removed-word only at the current
// (monotone) position, so stale bits ORed into already-passed words are harmless.
__global__ void matrix_kernel(const float4* __restrict__ cbox, const float* __restrict__ careas,
                              const uint32_t* __restrict__ ctrl, uint64_t* __restrict__ matrix) {
    int i = blockIdx.x;
    int M = (int)ctrl[0]; if (M > MMAX) M = MMAX;
    if (i >= M) return;
    int lane = threadIdx.x & 63;
    int wave = threadIdx.x >> 6;  // 4 waves per block
    float4 bi = cbox[i];
    float ai = careas[i];
    int w0 = i >> 6;
    for (int w = w0 + wave; w < MWORDS; w += 4) {
        int j = (w << 6) | lane;
        bool sup = false;
        if (j < M) {
            float4 bj = cbox[j];
            float xx1 = fmaxf(bi.x, bj.x);
            float yy1 = fmaxf(bi.y, bj.y);
            float xx2 = fminf(bi.z, bj.z);
            float yy2 = fminf(bi.w, bj.w);
            float inter = fmaxf(xx2 - xx1, 0.f) * fmaxf(yy2 - yy1, 0.f);
            float uni = ai + careas[j] - inter;
            float iou = inter / fmaxf(uni, 1e-8f);
            sup = iou > IOU_THR;
        }
        uint64_t word = __ballot(sup ? 1 : 0);
        if (lane == 0) matrix[(size_t)i * MWORDS + w] = word;
    }
}

// I: sequential greedy scan, one wave. Removed bitmask in lanes 0..31 (1 u64 each).
#define LOADBLK(ARR, b0)                                                       \
    {                                                                          \
        _Pragma("unroll")                                                      \
        for (int r_ = 0; r_ < 32; ++r_) {                                      \
            int row_ = (b0) + r_;                                              \
            row_ = row_ < MMAX ? row_ : MMAX - 1;                              \
            ARR[r_] = matrix[(size_t)row_ * MWORDS + (lane & 31)];             \
        }                                                                      \
    }

#define PROCBLK(ARR, b0, REFRESH_AT0)                                          \
    {                                                                          \
        _Pragma("unroll")                                                      \
        for (int r_ = 0; r_ < 32; ++r_) {                                      \
            int i_ = (b0) + r_;                                                \
            if ((REFRESH_AT0) && r_ == 0) {                                    \
                wrd = readlane_u64(removed, i_ >> 6);                          \
            }                                                                  \
            if (i_ < M && acc < MAX_BOXES && !((wrd >> (i_ & 63)) & 1ull)) {   \
                if (lane == 0) accepted[acc] = i_;                             \
                removed |= ARR[r_];                                            \
                wrd = readlane_u64(removed, i_ >> 6);                          \
                ++acc;                                                         \
            }                                                                  \
        }                                                                      \
    }

__global__ void scan_kernel(const uint64_t* __restrict__ matrix, uint32_t* __restrict__ ctrl,
                            int* __restrict__ accepted) {
    const int lane = threadIdx.x;
    int M = (int)ctrl[0]; if (M > MMAX) M = MMAX;
    uint64_t removed = 0;
    uint64_t wrd = 0;
    int acc = 0;
    uint64_t A[32], B[32];

    LOADBLK(A, 0);
    for (int base = 0; base < M && acc < MAX_BOXES; base += 64) {
        LOADBLK(B, base + 32);
        PROCBLK(A, base, true);
        LOADBLK(A, base + 64);
        PROCBLK(B, base + 32, false);
    }
    if (lane == 0) ctrl[1] = (uint32_t)acc;
}
#undef LOADBLK
#undef PROCBLK

// J: write all 25500 outputs (zeros for invalid slots)
__global__ void output_kernel(const float* __restrict__ boxes, const float* __restrict__ cls,
                              const int* __restrict__ csorted_idx, const int* __restrict__ accepted,
                              const uint32_t* __restrict__ ctrl, float* __restrict__ out, int total) {
    int e = blockIdx.x * blockDim.x + threadIdx.x;
    if (e >= total) return;
    int acc = (int)ctrl[1];
    float val = 0.0f;
    if (e < MAX_BOXES * 4) {
        int s = e >> 2, f = e & 3;
        if (s < acc) {
            int orig = csorted_idx[accepted[s]];
            val = boxes[(size_t)orig * 4 + f];
        }
    } else {
        int e2 = e - MAX_BOXES * 4;
        int s = e2 / NUM_CLASSES;
        int c = e2 - s * NUM_CLASSES;
        if (s < acc) {
            int orig = csorted_idx[accepted[s]];
            val = cls[(size_t)orig * NUM_CLASSES + c];
        }
    }
    out[e] = val;
}

extern "C" void kernel_launch(void* const* d_in, const int* in_sizes, int n_in,
                              void* d_out, int out_size, void* d_ws, size_t ws_size,
                              hipStream_t stream) {
    const float* boxes = (const float*)d_in[0];
    const float* cls   = (const float*)d_in[1];
    float* out = (float*)d_out;
    const int N = in_sizes[0] / 4;

    char* ws = (char*)d_ws;
    float*     scores      = (float*)(ws + OFF_SCORES);
    float*     careas      = (float*)(ws + OFF_CAREA);
    uint32_t*  coarse      = (uint32_t*)(ws + OFF_COARSE);
    uint32_t*  fine        = (uint32_t*)(ws + OFF_FINE);
    uint32_t*  ctrl        = (uint32_t*)(ws + OFF_CTRL);
    uint32_t*  rank        = (uint32_t*)(ws + OFF_RANK);
    uint64_t*  keys        = (uint64_t*)(ws + OFF_KEYS);
    int*       csorted_idx = (int*)(ws + OFF_CIDX);
    float4*    csorted_box = (float4*)(ws + OFF_CBOX);
    int*       accepted    = (int*)(ws + OFF_ACC);
    uint64_t*  matrix      = (uint64_t*)(ws + OFF_MATRIX);

    score_kernel<<<(N + 15) / 16, 256, 0, stream>>>(cls, scores, coarse, fine, ctrl, rank, N);
    coarse_hist_kernel<<<256, 256, 0, stream>>>(scores, coarse, N);
    fine_hist_kernel<<<256, 256, 0, stream>>>(scores, coarse, fine, N);
    compact_kernel<<<512, 256, 0, stream>>>(scores, coarse, fine, ctrl, keys, N);
    rank_partial_kernel<<<dim3(MMAX / 256, MMAX / 256), 256, 0, stream>>>(keys, ctrl, rank);
    scatter_kernel<<<MMAX / 256, 256, 0, stream>>>(keys, rank, ctrl, boxes, csorted_idx,
                                                   csorted_box, careas);
    matrix_kernel<<<MMAX, 256, 0, stream>>>(csorted_box, careas, ctrl, matrix);
    scan_kernel<<<1, 64, 0, stream>>>(matrix, ctrl, accepted);
    output_kernel<<<(out_size + 255) / 256, 256, 0, stream>>>(boxes, cls, csorted_idx, accepted,
                                                              ctrl, out, out_size);
}

// Round 6
// 109.048 us; speedup vs baseline: 7.8658x; 1.2138x over previous
//
#include <hip/hip_runtime.h>
#include <stdint.h>

#define NUM_CLASSES 81
#define MAX_BOXES 300
#define NEG_SCORE (-1000000000.0f)
#define IOU_THR 0.4f
#define MMAX 2048
#define MWORDS (MMAX / 64)   // 32

// ---- workspace layout (bytes) ----
static constexpr size_t OFF_SCORES = 0;               // 300000 * 4 = 1.2 MB
static constexpr size_t OFF_CAREA  = 0x1F0000;        // MMAX f32 (8 KB)
static constexpr size_t OFF_COARSE = 0x200000;        // 256 u32
static constexpr size_t OFF_FINE   = 0x201000;        // 256 u32
static constexpr size_t OFF_CTRL   = 0x202000;        // [0]=cand_count [1]=acc_count
static constexpr size_t OFF_RANK   = 0x203000;        // MMAX u32 (8 KB)
static constexpr size_t OFF_KEYS   = 0x208000;        // MMAX u64 (16 KB)
static constexpr size_t OFF_CIDX   = 0x210000;        // MMAX int (8 KB)
static constexpr size_t OFF_CBOX   = 0x214000;        // MMAX float4 (32 KB)
static constexpr size_t OFF_ACC    = 0x224000;        // 300 int
static constexpr size_t OFF_MATRIX = 0x228000;        // MMAX * MWORDS u64 = 512 KB

__device__ __forceinline__ uint32_t float_ordered(float f) {
    uint32_t b = __float_as_uint(f);
    return (b & 0x80000000u) ? ~b : (b | 0x80000000u);
}

__device__ __forceinline__ uint64_t readlane_u64(uint64_t v, int srclane) {
    uint32_t lo = (uint32_t)__builtin_amdgcn_readlane((int)(uint32_t)v, srclane);
    uint32_t hi = (uint32_t)__builtin_amdgcn_readlane((int)(uint32_t)(v >> 32), srclane);
    return ((uint64_t)hi << 32) | lo;
}

// A: 16 lanes per box, direct coalesced global dword loads, no LDS, NO atomics.
// Lane q reads elements q, q+16, ..., q+64 (5 independent loads); lane 15 folds
// element 80. 4x shfl_xor reduce -> box max across the 16-lane group. Lane q==0
// holds element 0 (v[0]) for the argmax==0 test and writes the score.
// Block 0 additionally zeroes hists / counters / ranks (init fold).
__global__ void score_kernel(const float* __restrict__ cls, float* __restrict__ scores,
                             uint32_t* __restrict__ coarse, uint32_t* __restrict__ fine,
                             uint32_t* __restrict__ ctrl, uint32_t* __restrict__ rank, int n) {
    if (blockIdx.x == 0) {
        int t = threadIdx.x;
        if (t < 256) { coarse[t] = 0; fine[t] = 0; }
        if (t < 8) ctrl[t] = 0;
        for (int r = t; r < MMAX; r += 256) rank[r] = 0;
    }
    const int q = threadIdx.x & 15;
    const int box = blockIdx.x * 16 + (threadIdx.x >> 4);  // 256 thr = 16 boxes/block
    const int cbox = box < n ? box : n - 1;
    const float* row = cls + (size_t)cbox * NUM_CLASSES;

    float v[5];
    #pragma unroll
    for (int it = 0; it < 5; ++it) v[it] = row[it * 16 + q];
    float e80 = row[80];

    float m = v[0];
    #pragma unroll
    for (int it = 1; it < 5; ++it) m = fmaxf(m, v[it]);
    m = (q == 15) ? fmaxf(m, e80) : m;
    m = fmaxf(m, __shfl_xor(m, 1));
    m = fmaxf(m, __shfl_xor(m, 2));
    m = fmaxf(m, __shfl_xor(m, 4));
    m = fmaxf(m, __shfl_xor(m, 8));

    if (q == 0 && box < n) {
        scores[box] = (v[0] == m) ? NEG_SCORE : m;  // v[0]<=m always; equality => argmax==0
    }
}

// B: coarse 256-bin histogram on top-8 ordered bits (LDS aggregate -> global)
__global__ void coarse_hist_kernel(const float* __restrict__ scores, uint32_t* __restrict__ coarse, int n) {
    __shared__ uint32_t h[256];
    for (int t = threadIdx.x; t < 256; t += blockDim.x) h[t] = 0;
    __syncthreads();
    for (int i = blockIdx.x * blockDim.x + threadIdx.x; i < n; i += gridDim.x * blockDim.x) {
        uint32_t o = float_ordered(scores[i]);
        atomicAdd(&h[o >> 24], 1u);
    }
    __syncthreads();
    for (int t = threadIdx.x; t < 256; t += blockDim.x)
        if (h[t]) atomicAdd(&coarse[t], h[t]);
}

// pick the coarse bin C containing the MMAX-th element; returns -1 if total <= MMAX
__device__ __forceinline__ int select_coarse(const uint32_t* coarse, uint32_t* above_out) {
    uint32_t s = 0;
    for (int c = 255; c >= 0; --c) {
        uint32_t sc = s + coarse[c];
        if (sc > MMAX) { *above_out = s; return c; }
        s = sc;
    }
    *above_out = s;
    return -1;
}

// D: fine 256-bin histogram of elements inside coarse bin C (next 8 ordered bits)
__global__ void fine_hist_kernel(const float* __restrict__ scores, const uint32_t* __restrict__ coarse,
                                 uint32_t* __restrict__ fine, int n) {
    __shared__ int sC;
    __shared__ uint32_t h[256];
    if (threadIdx.x == 0) {
        uint32_t above;
        sC = select_coarse(coarse, &above);
    }
    for (int t = threadIdx.x; t < 256; t += blockDim.x) h[t] = 0;
    __syncthreads();
    int C = sC;
    if (C < 0) return;
    for (int i = blockIdx.x * blockDim.x + threadIdx.x; i < n; i += gridDim.x * blockDim.x) {
        uint32_t o = float_ordered(scores[i]);
        if ((int)(o >> 24) == C) atomicAdd(&h[(o >> 16) & 255u], 1u);
    }
    __syncthreads();
    for (int t = threadIdx.x; t < 256; t += blockDim.x)
        if (h[t]) atomicAdd(&fine[t], h[t]);
}

// F: compute 16-bit threshold (<= MMAX candidates), compact keys = (ordered<<32)|~idx
__global__ void compact_kernel(const float* __restrict__ scores, const uint32_t* __restrict__ coarse,
                               const uint32_t* __restrict__ fine, uint32_t* __restrict__ ctrl,
                               uint64_t* __restrict__ keys, int n) {
    __shared__ uint32_t sThr;
    if (threadIdx.x == 0) {
        uint32_t above;
        int C = select_coarse(coarse, &above);
        uint32_t thr;
        if (C < 0) {
            thr = 0;
        } else {
            uint32_t R = MMAX - above;
            uint32_t g = 0, F = 0;
            for (int f = 255; f >= 0; --f) {
                uint32_t gf = g + fine[f];
                if (gf > R) { F = (uint32_t)f + 1u; break; }
                g = gf;
            }
            thr = ((uint32_t)C << 8) | F;
        }
        sThr = thr;
    }
    __syncthreads();
    uint32_t thr = sThr;
    for (int i = blockIdx.x * blockDim.x + threadIdx.x; i < n; i += gridDim.x * blockDim.x) {
        uint32_t o = float_ordered(scores[i]);
        if ((o >> 16) >= thr) {
            uint32_t pos = atomicAdd(&ctrl[0], 1u);
            if (pos < MMAX)
                keys[pos] = ((uint64_t)o << 32) | (uint32_t)(~(uint32_t)i);
        }
    }
}

// G1: brute-force rank: rank[c] = #{j : key_j > key_c}, tiled 256x256 via LDS
__global__ void rank_partial_kernel(const uint64_t* __restrict__ keys, const uint32_t* __restrict__ ctrl,
                                    uint32_t* __restrict__ rank) {
    __shared__ uint64_t kk[256];
    int M = (int)ctrl[0]; if (M > MMAX) M = MMAX;
    int cbase = blockIdx.x * 256;
    int jbase = blockIdx.y * 256;
    if (cbase >= M || jbase >= M) return;
    int t = threadIdx.x;
    int j = jbase + t;
    kk[t] = (j < M) ? keys[j] : 0ull;  // 0 never exceeds a candidate key (top bit set)
    __syncthreads();
    int c = cbase + t;
    if (c >= M) return;
    uint64_t k = keys[c];
    int cnt = 0;
    #pragma unroll 8
    for (int u = 0; u < 256; ++u) cnt += (kk[u] > k) ? 1 : 0;
    if (cnt) atomicAdd(&rank[c], (uint32_t)cnt);
}

// G2: scatter into sorted order; gather candidate boxes + areas
__global__ void scatter_kernel(const uint64_t* __restrict__ keys, const uint32_t* __restrict__ rank,
                               const uint32_t* __restrict__ ctrl, const float* __restrict__ boxes,
                               int* __restrict__ csorted_idx, float4* __restrict__ csorted_box,
                               float* __restrict__ careas) {
    int M = (int)ctrl[0]; if (M > MMAX) M = MMAX;
    int c = blockIdx.x * blockDim.x + threadIdx.x;
    if (c >= M) return;
    uint64_t k = keys[c];
    uint32_t r = rank[c];
    uint32_t idx = ~(uint32_t)k;
    float4 b = *(const float4*)(boxes + (size_t)idx * 4);
    csorted_idx[r] = (int)idx;
    csorted_box[r] = b;
    careas[r] = fmaxf(b.z - b.x, 0.f) * fmaxf(b.w - b.y, 0.f);
}

// H: pairwise IoU suppression bitmask, upper-triangle words only (w >= i>>6).
__global__ void matrix_kernel(const float4* __restrict__ cbox, const float* __restrict__ careas,
                              const uint32_t* __restrict__ ctrl, uint64_t* __restrict__ matrix) {
    int i = blockIdx.x;
    int M = (int)ctrl[0]; if (M > MMAX) M = MMAX;
    if (i >= M) return;
    int lane = threadIdx.x & 63;
    int wave = threadIdx.x >> 6;  // 4 waves per block
    float4 bi = cbox[i];
    float ai = careas[i];
    int w0 = i >> 6;
    for (int w = w0 + wave; w < MWORDS; w += 4) {
        int j = (w << 6) | lane;
        bool sup = false;
        if (j < M) {
            float4 bj = cbox[j];
            float xx1 = fmaxf(bi.x, bj.x);
            float yy1 = fmaxf(bi.y, bj.y);
            float xx2 = fminf(bi.z, bj.z);
            float yy2 = fminf(bi.w, bj.w);
            float inter = fmaxf(xx2 - xx1, 0.f) * fmaxf(yy2 - yy1, 0.f);
            float uni = ai + careas[j] - inter;
            float iou = inter / fmaxf(uni, 1e-8f);
            sup = iou > IOU_THR;
        }
        uint64_t word = __ballot(sup ? 1 : 0);
        if (lane == 0) matrix[(size_t)i * MWORDS + w] = word;
    }
}

// I: sequential greedy scan, one wave. Removed bitmask in lanes 0..31 (1 u64 each).
// Rows are staged into LDS via global_load_lds (fire-and-forget DMA, no VGPRs),
// double-buffered in 64-row blocks; one s_waitcnt vmcnt(0) per block swap. Rows
// are consumed from LDS through a 16-deep rolling register window of ds_read_b64
// (constant-indexed, fully unrolled -> stays in VGPRs).
typedef const uint32_t __attribute__((address_space(1)))* glb_u32p;
typedef uint32_t __attribute__((address_space(3)))* lds_u32p;

__global__ void scan_kernel(const uint64_t* __restrict__ matrix, uint32_t* __restrict__ ctrl,
                            int* __restrict__ accepted) {
    __shared__ uint64_t sbuf[2][64][MWORDS];  // 2 x 16 KB
    const int lane = threadIdx.x;
    const int l31 = lane & 31;
    int M = (int)ctrl[0]; if (M > MMAX) M = MMAX;
    uint64_t removed = 0;
    uint64_t wrd = 0;
    int acc = 0;

    // stage one 64-row block: 64 x global_load_lds, each moves one 256-B row
    // (64 lanes x 4 B). LDS dest = uniform row base + lane*4; global src per-lane.
#define STAGE(BI, BASE)                                                          \
    {                                                                            \
        _Pragma("unroll")                                                        \
        for (int r_ = 0; r_ < 64; ++r_) {                                        \
            const uint32_t* gsrc =                                               \
                (const uint32_t*)(matrix + (size_t)((BASE) + r_) * MWORDS) + lane; \
            __builtin_amdgcn_global_load_lds((glb_u32p)gsrc,                     \
                                             (lds_u32p)&sbuf[BI][r_][0], 4, 0, 0); \
        }                                                                        \
    }

#define PROCESS(BI, BASE)                                                        \
    {                                                                            \
        uint64_t W[16];                                                          \
        _Pragma("unroll")                                                        \
        for (int w_ = 0; w_ < 16; ++w_) W[w_] = sbuf[BI][w_][l31];               \
        _Pragma("unroll")                                                        \
        for (int r_ = 0; r_ < 64; ++r_) {                                        \
            int i_ = (BASE) + r_;                                                \
            uint64_t row = W[r_ & 15];                                           \
            if (r_ + 16 < 64) W[r_ & 15] = sbuf[BI][r_ + 16][l31];               \
            if (r_ == 0) wrd = readlane_u64(removed, i_ >> 6);                   \
            if (i_ < M && acc < MAX_BOXES && !((wrd >> (i_ & 63)) & 1ull)) {     \
                if (lane == 0) accepted[acc] = i_;                               \
                removed |= row;                                                  \
                wrd = readlane_u64(removed, i_ >> 6);                            \
                ++acc;                                                           \
            }                                                                    \
        }                                                                        \
    }

    int nblocks = (M + 63) >> 6;
    if (nblocks > 0) {
        STAGE(0, 0);
        asm volatile("s_waitcnt vmcnt(0)" ::: "memory");
        int bi = 0;
        for (int b = 0; b < nblocks && acc < MAX_BOXES; ++b) {
            if (b + 1 < nblocks) STAGE(bi ^ 1, (b + 1) << 6);
            PROCESS(bi, b << 6);
            asm volatile("s_waitcnt vmcnt(0)" ::: "memory");
            bi ^= 1;
        }
    }
#undef STAGE
#undef PROCESS
    if (lane == 0) ctrl[1] = (uint32_t)acc;
}

// J: write all 25500 outputs (zeros for invalid slots)
__global__ void output_kernel(const float* __restrict__ boxes, const float* __restrict__ cls,
                              const int* __restrict__ csorted_idx, const int* __restrict__ accepted,
                              const uint32_t* __restrict__ ctrl, float* __restrict__ out, int total) {
    int e = blockIdx.x * blockDim.x + threadIdx.x;
    if (e >= total) return;
    int acc = (int)ctrl[1];
    float val = 0.0f;
    if (e < MAX_BOXES * 4) {
        int s = e >> 2, f = e & 3;
        if (s < acc) {
            int orig = csorted_idx[accepted[s]];
            val = boxes[(size_t)orig * 4 + f];
        }
    } else {
        int e2 = e - MAX_BOXES * 4;
        int s = e2 / NUM_CLASSES;
        int c = e2 - s * NUM_CLASSES;
        if (s < acc) {
            int orig = csorted_idx[accepted[s]];
            val = cls[(size_t)orig * NUM_CLASSES + c];
        }
    }
    out[e] = val;
}

extern "C" void kernel_launch(void* const* d_in, const int* in_sizes, int n_in,
                              void* d_out, int out_size, void* d_ws, size_t ws_size,
                              hipStream_t stream) {
    const float* boxes = (const float*)d_in[0];
    const float* cls   = (const float*)d_in[1];
    float* out = (float*)d_out;
    const int N = in_sizes[0] / 4;

    char* ws = (char*)d_ws;
    float*     scores      = (float*)(ws + OFF_SCORES);
    float*     careas      = (float*)(ws + OFF_CAREA);
    uint32_t*  coarse      = (uint32_t*)(ws + OFF_COARSE);
    uint32_t*  fine        = (uint32_t*)(ws + OFF_FINE);
    uint32_t*  ctrl        = (uint32_t*)(ws + OFF_CTRL);
    uint32_t*  rank        = (uint32_t*)(ws + OFF_RANK);
    uint64_t*  keys        = (uint64_t*)(ws + OFF_KEYS);
    int*       csorted_idx = (int*)(ws + OFF_CIDX);
    float4*    csorted_box = (float4*)(ws + OFF_CBOX);
    int*       accepted    = (int*)(ws + OFF_ACC);
    uint64_t*  matrix      = (uint64_t*)(ws + OFF_MATRIX);

    score_kernel<<<(N + 15) / 16, 256, 0, stream>>>(cls, scores, coarse, fine, ctrl, rank, N);
    coarse_hist_kernel<<<256, 256, 0, stream>>>(scores, coarse, N);
    fine_hist_kernel<<<256, 256, 0, stream>>>(scores, coarse, fine, N);
    compact_kernel<<<512, 256, 0, stream>>>(scores, coarse, fine, ctrl, keys, N);
    rank_partial_kernel<<<dim3(MMAX / 256, MMAX / 256), 256, 0, stream>>>(keys, ctrl, rank);
    scatter_kernel<<<MMAX / 256, 256, 0, stream>>>(keys, rank, ctrl, boxes, csorted_idx,
                                                   csorted_box, careas);
    matrix_kernel<<<MMAX, 256, 0, stream>>>(csorted_box, careas, ctrl, matrix);
    scan_kernel<<<1, 64, 0, stream>>>(matrix, ctrl, accepted);
    output_kernel<<<(out_size + 255) / 256, 256, 0, stream>>>(boxes, cls, csorted_idx, accepted,
                                                              ctrl, out, out_size);
}